// Round 13
// baseline (176.734 us; speedup 1.0000x reference)
//
#include <hip/hip_runtime.h>

// MHA: B=8, N=1024, D=768, H=12, HD=64. FLOAT32 in/out, bf16 MFMA internally.
// Round 13: round-12 lessons applied to qkv/out_proj.
// qkv: staged x-tile (coalesced f32->bf16 LDS), transposed compute (A=W^T,
//      B=x) -> packed 8B Q/K stores, LDS-collected coalesced Vt stores.
// out_proj: transposed compute (A=Wo, B=AO) -> float4 Y stores.
// attn (47.5us, round 12) and prep unchanged.

typedef __attribute__((ext_vector_type(8))) short short8;   // 8 x bf16 bits
typedef __attribute__((ext_vector_type(4))) float floatx4;  // MFMA acc

#define MFMA16(a, b, c) __builtin_amdgcn_mfma_f32_16x16x32_bf16((a), (b), (c), 0, 0, 0)

#if __has_builtin(__builtin_amdgcn_exp2f)
#define EXP2(x) __builtin_amdgcn_exp2f(x)
#else
#define EXP2(x) __expf(0.6931471805599453f * (x))
#endif
#if __has_builtin(__builtin_amdgcn_rcpf)
#define RCP(x) __builtin_amdgcn_rcpf(x)
#else
#define RCP(x) (1.0f / (x))
#endif

__device__ __forceinline__ unsigned short f2bf(float f) {
    union { float f; unsigned int i; } c;
    c.f = f;
    unsigned int i = c.i;
    return (unsigned short)((i + 0x7fffu + ((i >> 16) & 1u)) >> 16);  // RNE
}
__device__ __forceinline__ unsigned short f2bf_trunc(float f) {
    union { float f; unsigned int i; } c;
    c.f = f;
    return (unsigned short)(c.i >> 16);
}

// ---------------------------------------------------------------------------
// Phase 0: Wt[h][e][k] = W[h][k][e] (bf16), Wo_bf = bf16(Wo).
// ---------------------------------------------------------------------------
__global__ __launch_bounds__(256) void prep_weights(
    const float* __restrict__ Wq, const float* __restrict__ Wk,
    const float* __restrict__ Wv, const float* __restrict__ Wo,
    unsigned short* __restrict__ Wqt, unsigned short* __restrict__ Wkt,
    unsigned short* __restrict__ Wvt, unsigned short* __restrict__ Wob)
{
    int tid = blockIdx.x * 256 + threadIdx.x;  // 0..147455
    if (tid < 49152) {                          // 12 heads * 4096 only
        int h = tid >> 12, r = tid & 4095;
        int e = r >> 6, k = r & 63;
        int src = h * 4096 + k * 64 + e, dst = h * 4096 + e * 64 + k;
        Wqt[dst] = f2bf(Wq[src]);
        Wkt[dst] = f2bf(Wk[src]);
        Wvt[dst] = f2bf(Wv[src]);
    }
    for (int i = tid; i < 589824; i += 147456) Wob[i] = f2bf(Wo[i]);
}

// ---------------------------------------------------------------------------
// Phase 1: staged + transposed QKV. grid (16, 96), block 256 (4 waves).
// Stage x[64 seq][64 k] f32->bf16 into padded LDS (coalesced 64B/thread).
// Compute D[e][seq] with A = Wt fragment (contiguous), B = x fragment (LDS).
// Q/K: lane holds fixed seq, 4 consecutive e -> packed 8B stores.
// V: collected in LDS, then cooperative coalesced 16B stores to Vt[e][seq].
// ---------------------------------------------------------------------------
__global__ __launch_bounds__(256) void qkv_proj(
    const float* __restrict__ x,
    const unsigned short* __restrict__ Wqt, const unsigned short* __restrict__ Wkt,
    const unsigned short* __restrict__ Wvt,
    const float* __restrict__ bq, const float* __restrict__ bk,
    const float* __restrict__ bv,
    unsigned short* __restrict__ Q, unsigned short* __restrict__ K,
    unsigned short* __restrict__ Vt)
{
    __shared__ __align__(16) unsigned short xlds[64 * 72];  // 9216 B
    __shared__ __align__(16) unsigned short vlds[64 * 72];  // 9216 B

    const int bh = blockIdx.y;
    const int b = bh / 12, h = bh % 12;
    const int wave = threadIdx.x >> 6, lane = threadIdx.x & 63;
    const int lrow = lane & 15, quad = lane >> 4;
    const int row0 = blockIdx.x * 64;
    const float scale = 0.052058776672f;  // 768^-0.5 * log2(e): p = 2^s

    // ---- stage x tile (coalesced: 4 threads cover one row's 64 f32) ----
    {
        const int tr = threadIdx.x >> 2;   // seq row 0..63
        const int tc = threadIdx.x & 3;    // chunk of 16 f32
        const float* src = x + ((size_t)(b * 1024 + row0 + tr)) * 768
                           + h * 64 + tc * 16;
        float4 f0 = *(const float4*)(src);
        float4 f1 = *(const float4*)(src + 4);
        float4 f2 = *(const float4*)(src + 8);
        float4 f3 = *(const float4*)(src + 12);
        short8 p0, p1;
        p0[0] = (short)f2bf(f0.x); p0[1] = (short)f2bf(f0.y);
        p0[2] = (short)f2bf(f0.z); p0[3] = (short)f2bf(f0.w);
        p0[4] = (short)f2bf(f1.x); p0[5] = (short)f2bf(f1.y);
        p0[6] = (short)f2bf(f1.z); p0[7] = (short)f2bf(f1.w);
        p1[0] = (short)f2bf(f2.x); p1[1] = (short)f2bf(f2.y);
        p1[2] = (short)f2bf(f2.z); p1[3] = (short)f2bf(f2.w);
        p1[4] = (short)f2bf(f3.x); p1[5] = (short)f2bf(f3.y);
        p1[6] = (short)f2bf(f3.z); p1[7] = (short)f2bf(f3.w);
        *(short8*)&xlds[tr * 72 + tc * 16] = p0;
        *(short8*)&xlds[tr * 72 + tc * 16 + 8] = p1;
    }
    __syncthreads();

    // x fragments (B-operand: n=seq=lane&15 within wave tile, k=quad*8+j)
    short8 xb0 = *(const short8*)&xlds[(wave * 16 + lrow) * 72 + quad * 8];
    short8 xb1 = *(const short8*)&xlds[(wave * 16 + lrow) * 72 + 32 + quad * 8];

    const floatx4 zero = { 0.f, 0.f, 0.f, 0.f };

    // ---- Q and K (D[e][seq]: lane fixed seq, e = t*16+quad*4+r) ----
    const unsigned short* Wm[2] = { Wqt + h * 4096, Wkt + h * 4096 };
    const float* bm[2] = { bq + h * 64, bk + h * 64 };
    unsigned short* Om[2] = {
        Q + ((size_t)bh * 1024 + row0 + wave * 16 + lrow) * 64,
        K + ((size_t)bh * 1024 + row0 + wave * 16 + lrow) * 64 };
    #pragma unroll
    for (int m = 0; m < 2; ++m) {
        const unsigned short* W = Wm[m];
        #pragma unroll
        for (int t = 0; t < 4; ++t) {
            // A-operand: Wt[e = t*16+lrow][k] contiguous
            short8 wa0 = *(const short8*)(W + (t * 16 + lrow) * 64 + quad * 8);
            short8 wa1 = *(const short8*)(W + (t * 16 + lrow) * 64 + 32 + quad * 8);
            floatx4 acc = zero;
            acc = MFMA16(wa0, xb0, acc);
            acc = MFMA16(wa1, xb1, acc);
            float4 bias = *(const float4*)(bm[m] + t * 16 + quad * 4);
            const float bs[4] = { bias.x, bias.y, bias.z, bias.w };
            unsigned short pkd[4];
            #pragma unroll
            for (int r = 0; r < 4; ++r) {
                float v = acc[r] + bs[r];
                if (m == 0) v *= scale;
                pkd[r] = f2bf(v);
            }
            *(uint2*)(Om[m] + t * 16 + quad * 4) = *(uint2*)pkd;  // 8B store
        }
    }

    // ---- V: D[e][seq] -> LDS collect -> coalesced Vt store ----
    {
        const unsigned short* W = Wvt + h * 4096;
        const float* bvh = bv + h * 64;
        #pragma unroll
        for (int t = 0; t < 4; ++t) {
            short8 wa0 = *(const short8*)(W + (t * 16 + lrow) * 64 + quad * 8);
            short8 wa1 = *(const short8*)(W + (t * 16 + lrow) * 64 + 32 + quad * 8);
            floatx4 acc = zero;
            acc = MFMA16(wa0, xb0, acc);
            acc = MFMA16(wa1, xb1, acc);
            float4 bias = *(const float4*)(bvh + t * 16 + quad * 4);
            const float bs[4] = { bias.x, bias.y, bias.z, bias.w };
            #pragma unroll
            for (int r = 0; r < 4; ++r)
                vlds[(t * 16 + quad * 4 + r) * 72 + wave * 16 + lrow]
                    = f2bf(acc[r] + bs[r]);
        }
    }
    __syncthreads();
    {
        const int er = threadIdx.x >> 2;   // e row 0..63
        const int sc = threadIdx.x & 3;    // chunk of 16 seq
        short8 v0 = *(const short8*)&vlds[er * 72 + sc * 16];
        short8 v1 = *(const short8*)&vlds[er * 72 + sc * 16 + 8];
        unsigned short* dst = Vt + (size_t)bh * 65536 + (size_t)er * 1024
                              + row0 + sc * 16;
        *(short8*)dst = v0;
        *(short8*)(dst + 8) = v1;
    }
}

// ---------------------------------------------------------------------------
// Phase 2 (round-12 version, unchanged): staged K/V + register-only P.
// ---------------------------------------------------------------------------
__global__ __launch_bounds__(256) void attn_kernel(
    const unsigned short* __restrict__ Q, const unsigned short* __restrict__ K,
    const unsigned short* __restrict__ Vt, unsigned short* __restrict__ AO)
{
    __shared__ __align__(16) unsigned short Klds[64 * 72];  // 9216 B
    __shared__ __align__(16) unsigned short Vlds[64 * 72];  // 9216 B

    const int id = blockIdx.x + 16 * blockIdx.y;         // flat, x-fastest
    const int bh = (id & 7) * 12 + ((id % 96) >> 3);     // XCD-clustered bh
    const int qb = id / 96;                              // 0..15
    const int b = bh / 12, h = bh % 12;
    const int wave = threadIdx.x >> 6, lane = threadIdx.x & 63;
    const int lrow = lane & 15, quad = lane >> 4;
    const int qrow0 = qb * 64 + wave * 16;

    const unsigned short* Qb = Q + (size_t)bh * 65536;
    const unsigned short* Kb = K + (size_t)bh * 65536;
    const unsigned short* Vb = Vt + (size_t)bh * 65536;

    const int tch = threadIdx.x & 7, trow = threadIdx.x >> 3;

    short8 aq0, aq1;
    {
        const unsigned short* qr = Qb + (size_t)(qrow0 + lrow) * 64;
        aq0 = *(const short8*)(qr + quad * 8);
        aq1 = *(const short8*)(qr + 32 + quad * 8);
    }

    const int krow_base = ((lrow >> 2) * 8) + (lrow & 3);

    const floatx4 zero = { 0.f, 0.f, 0.f, 0.f };
    float part = 0.f;
    floatx4 Oacc[4];
    #pragma unroll
    for (int t = 0; t < 4; ++t) Oacc[t] = zero;

    for (int jt = 0; jt < 16; ++jt) {
        const int j0 = jt * 64;

        #pragma unroll
        for (int rr = 0; rr < 2; ++rr) {
            int r = trow + rr * 32;
            *(short8*)&Klds[r * 72 + tch * 8] =
                *(const short8*)(Kb + (size_t)(j0 + r) * 64 + tch * 8);
            *(short8*)&Vlds[r * 72 + tch * 8] =
                *(const short8*)(Vb + (size_t)r * 1024 + j0 + tch * 8);
        }
        __syncthreads();

        #pragma unroll
        for (int w = 0; w < 2; ++w) {
            short8 kA[2][2];
            #pragma unroll
            for (int tau = 0; tau < 2; ++tau) {
                int kr = w * 32 + krow_base + 4 * tau;
                kA[tau][0] = *(const short8*)&Klds[kr * 72 + quad * 8];
                kA[tau][1] = *(const short8*)&Klds[kr * 72 + 32 + quad * 8];
            }
            short8 vA[4];
            #pragma unroll
            for (int t = 0; t < 4; ++t)
                vA[t] = *(const short8*)&Vlds[(t * 16 + lrow) * 72
                                              + w * 32 + quad * 8];

            floatx4 s0 = zero, s1 = zero;
            s0 = MFMA16(kA[0][0], aq0, s0);
            s0 = MFMA16(kA[0][1], aq1, s0);
            s1 = MFMA16(kA[1][0], aq0, s1);
            s1 = MFMA16(kA[1][1], aq1, s1);

            short8 pk;
            #pragma unroll
            for (int r = 0; r < 4; ++r) {
                float p0 = EXP2(s0[r]);
                float p1 = EXP2(s1[r]);
                part += p0 + p1;
                pk[r] = (short)f2bf_trunc(p0);
                pk[4 + r] = (short)f2bf_trunc(p1);
            }
            #pragma unroll
            for (int t = 0; t < 4; ++t)
                Oacc[t] = MFMA16(vA[t], pk, Oacc[t]);
        }
        __syncthreads();
    }

    float ts = part;
    ts += __shfl_xor(ts, 16);
    ts += __shfl_xor(ts, 32);
    float inv = RCP(ts);
    unsigned short* orow = AO
        + ((size_t)(b * 1024 + qrow0 + lrow)) * 768 + h * 64;
    #pragma unroll
    for (int t = 0; t < 4; ++t) {
        unsigned short pkd[4];
        #pragma unroll
        for (int r = 0; r < 4; ++r)
            pkd[r] = f2bf(Oacc[t][r] * inv);
        *(uint2*)(orow + t * 16 + quad * 4) = *(uint2*)pkd;
    }
}

// ---------------------------------------------------------------------------
// Phase 3: staged GEMM, transposed compute. D[c][row] (A=Wo frag, B=AO frag)
// -> lane holds fixed row, 4 consecutive c -> float4 Y stores.
// Tile 128x64, BK=32. grid (64, 12), block 256 = 2x2 waves of 64row x 32c.
// ---------------------------------------------------------------------------
__global__ __launch_bounds__(256) void out_proj(
    const unsigned short* __restrict__ AO, const unsigned short* __restrict__ Wob,
    const float* __restrict__ bo, float* __restrict__ Y)
{
    __shared__ __align__(16) unsigned short Alds[128 * 40];  // 10240 B
    __shared__ __align__(16) unsigned short Blds[64 * 40];   //  5120 B

    const int wave = threadIdx.x >> 6, lane = threadIdx.x & 63;
    const int lrow = lane & 15, quad = lane >> 4;
    const int row0 = blockIdx.x * 128;
    const int c0 = blockIdx.y * 64;
    const int wrow = (wave >> 1) * 64, wcol = (wave & 1) * 32;

    const int tch = threadIdx.x & 3, trow = threadIdx.x >> 2;  // 64 rows/round

    const floatx4 zero = { 0.f, 0.f, 0.f, 0.f };
    floatx4 acc[2][4];  // [c-subtile u][row-subtile t]
    #pragma unroll
    for (int u = 0; u < 2; ++u)
        #pragma unroll
        for (int t = 0; t < 4; ++t) acc[u][t] = zero;

    for (int k0 = 0; k0 < 768; k0 += 32) {
        #pragma unroll
        for (int rr = 0; rr < 2; ++rr) {
            int r = trow + rr * 64;
            *(short8*)&Alds[r * 40 + tch * 8] =
                *(const short8*)(AO + (size_t)(row0 + r) * 768 + k0 + tch * 8);
        }
        *(short8*)&Blds[trow * 40 + tch * 8] =
            *(const short8*)(Wob + (size_t)(c0 + trow) * 768 + k0 + tch * 8);
        __syncthreads();

        short8 aoF[4], wF[2];
        #pragma unroll
        for (int t = 0; t < 4; ++t)
            aoF[t] = *(const short8*)&Alds[(wrow + t * 16 + lrow) * 40 + quad * 8];
        #pragma unroll
        for (int u = 0; u < 2; ++u)
            wF[u] = *(const short8*)&Blds[(wcol + u * 16 + lrow) * 40 + quad * 8];

        #pragma unroll
        for (int u = 0; u < 2; ++u)
            #pragma unroll
            for (int t = 0; t < 4; ++t)
                acc[u][t] = MFMA16(wF[u], aoF[t], acc[u][t]);  // D[c][row]
        __syncthreads();
    }

    #pragma unroll
    for (int u = 0; u < 2; ++u) {
        const int cb = c0 + wcol + u * 16 + quad * 4;
        float4 bias = *(const float4*)(bo + cb);
        const float bs[4] = { bias.x, bias.y, bias.z, bias.w };
        #pragma unroll
        for (int t = 0; t < 4; ++t) {
            const int row = row0 + wrow + t * 16 + lrow;
            float out[4];
            #pragma unroll
            for (int r = 0; r < 4; ++r) out[r] = acc[u][t][r] + bs[r];
            *(float4*)(Y + (size_t)row * 768 + cb) = *(float4*)out;  // 16B store
        }
    }
}

extern "C" void kernel_launch(void* const* d_in, const int* in_sizes, int n_in,
                              void* d_out, int out_size, void* d_ws, size_t ws_size,
                              hipStream_t stream)
{
    const float* x  = (const float*)d_in[0];
    const float* Wq = (const float*)d_in[1];
    const float* Wk = (const float*)d_in[2];
    const float* Wv = (const float*)d_in[3];
    const float* bq = (const float*)d_in[4];
    const float* bk = (const float*)d_in[5];
    const float* bv = (const float*)d_in[6];
    const float* Wo = (const float*)d_in[7];
    const float* bo = (const float*)d_in[8];

    // ws layout (bf16 elements)
    unsigned short* Q   = (unsigned short*)d_ws;        // 6291456
    unsigned short* K   = Q + 6291456;                  // 6291456
    unsigned short* Vt  = K + 6291456;                  // 6291456 (transposed)
    unsigned short* AO  = Vt + 6291456;                 // 6291456
    unsigned short* Wqt = AO + 6291456;                 // 49152
    unsigned short* Wkt = Wqt + 49152;                  // 49152
    unsigned short* Wvt = Wkt + 49152;                  // 49152
    unsigned short* Wob = Wvt + 49152;                  // 589824
    float* Y = (float*)d_out;

    prep_weights<<<dim3(576), 256, 0, stream>>>(Wq, Wk, Wv, Wo, Wqt, Wkt, Wvt, Wob);
    qkv_proj<<<dim3(16, 96), 256, 0, stream>>>(x, Wqt, Wkt, Wvt, bq, bk, bv, Q, K, Vt);
    attn_kernel<<<dim3(16, 96), 256, 0, stream>>>(Q, K, Vt, AO);
    out_proj<<<dim3(64, 12), 256, 0, stream>>>(AO, Wob, bo, Y);
}

// Round 14
// 173.369 us; speedup vs baseline: 1.0194x; 1.0194x over previous
//
#include <hip/hip_runtime.h>

// MHA: B=8, N=1024, D=768, H=12, HD=64. FLOAT32 in/out, bf16 MFMA internally.
// Round 14: attn upgraded — M=32/wave (32 MFMA per staged tile), prefetch
// staging (next tile's global loads in flight under compute), slot-permuted
// K LDS layout (linear fragment reads, 2-way bank alias = free).
// qkv/out_proj/prep unchanged from round 13.

typedef __attribute__((ext_vector_type(8))) short short8;   // 8 x bf16 bits
typedef __attribute__((ext_vector_type(4))) float floatx4;  // MFMA acc

#define MFMA16(a, b, c) __builtin_amdgcn_mfma_f32_16x16x32_bf16((a), (b), (c), 0, 0, 0)

#if __has_builtin(__builtin_amdgcn_exp2f)
#define EXP2(x) __builtin_amdgcn_exp2f(x)
#else
#define EXP2(x) __expf(0.6931471805599453f * (x))
#endif
#if __has_builtin(__builtin_amdgcn_rcpf)
#define RCP(x) __builtin_amdgcn_rcpf(x)
#else
#define RCP(x) (1.0f / (x))
#endif

__device__ __forceinline__ unsigned short f2bf(float f) {
    union { float f; unsigned int i; } c;
    c.f = f;
    unsigned int i = c.i;
    return (unsigned short)((i + 0x7fffu + ((i >> 16) & 1u)) >> 16);  // RNE
}
__device__ __forceinline__ unsigned short f2bf_trunc(float f) {
    union { float f; unsigned int i; } c;
    c.f = f;
    return (unsigned short)(c.i >> 16);
}

// ---------------------------------------------------------------------------
// Phase 0: Wt[h][e][k] = W[h][k][e] (bf16), Wo_bf = bf16(Wo).
// ---------------------------------------------------------------------------
__global__ __launch_bounds__(256) void prep_weights(
    const float* __restrict__ Wq, const float* __restrict__ Wk,
    const float* __restrict__ Wv, const float* __restrict__ Wo,
    unsigned short* __restrict__ Wqt, unsigned short* __restrict__ Wkt,
    unsigned short* __restrict__ Wvt, unsigned short* __restrict__ Wob)
{
    int tid = blockIdx.x * 256 + threadIdx.x;  // 0..147455
    if (tid < 49152) {                          // 12 heads * 4096 only
        int h = tid >> 12, r = tid & 4095;
        int e = r >> 6, k = r & 63;
        int src = h * 4096 + k * 64 + e, dst = h * 4096 + e * 64 + k;
        Wqt[dst] = f2bf(Wq[src]);
        Wkt[dst] = f2bf(Wk[src]);
        Wvt[dst] = f2bf(Wv[src]);
    }
    for (int i = tid; i < 589824; i += 147456) Wob[i] = f2bf(Wo[i]);
}

// ---------------------------------------------------------------------------
// Phase 1 (round-13): staged + transposed QKV. grid (16, 96), block 256.
// ---------------------------------------------------------------------------
__global__ __launch_bounds__(256) void qkv_proj(
    const float* __restrict__ x,
    const unsigned short* __restrict__ Wqt, const unsigned short* __restrict__ Wkt,
    const unsigned short* __restrict__ Wvt,
    const float* __restrict__ bq, const float* __restrict__ bk,
    const float* __restrict__ bv,
    unsigned short* __restrict__ Q, unsigned short* __restrict__ K,
    unsigned short* __restrict__ Vt)
{
    __shared__ __align__(16) unsigned short xlds[64 * 72];  // 9216 B
    __shared__ __align__(16) unsigned short vlds[64 * 72];  // 9216 B

    const int bh = blockIdx.y;
    const int b = bh / 12, h = bh % 12;
    const int wave = threadIdx.x >> 6, lane = threadIdx.x & 63;
    const int lrow = lane & 15, quad = lane >> 4;
    const int row0 = blockIdx.x * 64;
    const float scale = 0.052058776672f;  // 768^-0.5 * log2(e): p = 2^s

    {
        const int tr = threadIdx.x >> 2;   // seq row 0..63
        const int tc = threadIdx.x & 3;    // chunk of 16 f32
        const float* src = x + ((size_t)(b * 1024 + row0 + tr)) * 768
                           + h * 64 + tc * 16;
        float4 f0 = *(const float4*)(src);
        float4 f1 = *(const float4*)(src + 4);
        float4 f2 = *(const float4*)(src + 8);
        float4 f3 = *(const float4*)(src + 12);
        short8 p0, p1;
        p0[0] = (short)f2bf(f0.x); p0[1] = (short)f2bf(f0.y);
        p0[2] = (short)f2bf(f0.z); p0[3] = (short)f2bf(f0.w);
        p0[4] = (short)f2bf(f1.x); p0[5] = (short)f2bf(f1.y);
        p0[6] = (short)f2bf(f1.z); p0[7] = (short)f2bf(f1.w);
        p1[0] = (short)f2bf(f2.x); p1[1] = (short)f2bf(f2.y);
        p1[2] = (short)f2bf(f2.z); p1[3] = (short)f2bf(f2.w);
        p1[4] = (short)f2bf(f3.x); p1[5] = (short)f2bf(f3.y);
        p1[6] = (short)f2bf(f3.z); p1[7] = (short)f2bf(f3.w);
        *(short8*)&xlds[tr * 72 + tc * 16] = p0;
        *(short8*)&xlds[tr * 72 + tc * 16 + 8] = p1;
    }
    __syncthreads();

    short8 xb0 = *(const short8*)&xlds[(wave * 16 + lrow) * 72 + quad * 8];
    short8 xb1 = *(const short8*)&xlds[(wave * 16 + lrow) * 72 + 32 + quad * 8];

    const floatx4 zero = { 0.f, 0.f, 0.f, 0.f };

    const unsigned short* Wm[2] = { Wqt + h * 4096, Wkt + h * 4096 };
    const float* bm[2] = { bq + h * 64, bk + h * 64 };
    unsigned short* Om[2] = {
        Q + ((size_t)bh * 1024 + row0 + wave * 16 + lrow) * 64,
        K + ((size_t)bh * 1024 + row0 + wave * 16 + lrow) * 64 };
    #pragma unroll
    for (int m = 0; m < 2; ++m) {
        const unsigned short* W = Wm[m];
        #pragma unroll
        for (int t = 0; t < 4; ++t) {
            short8 wa0 = *(const short8*)(W + (t * 16 + lrow) * 64 + quad * 8);
            short8 wa1 = *(const short8*)(W + (t * 16 + lrow) * 64 + 32 + quad * 8);
            floatx4 acc = zero;
            acc = MFMA16(wa0, xb0, acc);
            acc = MFMA16(wa1, xb1, acc);
            float4 bias = *(const float4*)(bm[m] + t * 16 + quad * 4);
            const float bs[4] = { bias.x, bias.y, bias.z, bias.w };
            unsigned short pkd[4];
            #pragma unroll
            for (int r = 0; r < 4; ++r) {
                float v = acc[r] + bs[r];
                if (m == 0) v *= scale;
                pkd[r] = f2bf(v);
            }
            *(uint2*)(Om[m] + t * 16 + quad * 4) = *(uint2*)pkd;  // 8B store
        }
    }

    {
        const unsigned short* W = Wvt + h * 4096;
        const float* bvh = bv + h * 64;
        #pragma unroll
        for (int t = 0; t < 4; ++t) {
            short8 wa0 = *(const short8*)(W + (t * 16 + lrow) * 64 + quad * 8);
            short8 wa1 = *(const short8*)(W + (t * 16 + lrow) * 64 + 32 + quad * 8);
            floatx4 acc = zero;
            acc = MFMA16(wa0, xb0, acc);
            acc = MFMA16(wa1, xb1, acc);
            float4 bias = *(const float4*)(bvh + t * 16 + quad * 4);
            const float bs[4] = { bias.x, bias.y, bias.z, bias.w };
            #pragma unroll
            for (int r = 0; r < 4; ++r)
                vlds[(t * 16 + quad * 4 + r) * 72 + wave * 16 + lrow]
                    = f2bf(acc[r] + bs[r]);
        }
    }
    __syncthreads();
    {
        const int er = threadIdx.x >> 2;   // e row 0..63
        const int sc = threadIdx.x & 3;    // chunk of 16 seq
        short8 v0 = *(const short8*)&vlds[er * 72 + sc * 16];
        short8 v1 = *(const short8*)&vlds[er * 72 + sc * 16 + 8];
        unsigned short* dst = Vt + (size_t)bh * 65536 + (size_t)er * 1024
                              + row0 + sc * 16;
        *(short8*)dst = v0;
        *(short8*)(dst + 8) = v1;
    }
}

// ---------------------------------------------------------------------------
// Phase 2: flash attention. grid (8, 96), block 256 = 4 waves x 32 q-rows
// (2 m-tiles each), full 1024-KV sweep in 16 tiles of 64.
// bx = bh%8 (XCD pin: all 8 q-blocks of a bh share bx -> one XCD's L2).
// Staging is PREFETCHED (next tile's global loads issued before compute) and
// K rows are stored slot-permuted so fragment reads are linear in lane.
// Register-only S^T -> exp -> pack -> PV transform (P never in LDS).
// ---------------------------------------------------------------------------
__global__ __launch_bounds__(256) void attn_kernel(
    const unsigned short* __restrict__ Q, const unsigned short* __restrict__ K,
    const unsigned short* __restrict__ Vt, unsigned short* __restrict__ AO)
{
    __shared__ __align__(16) unsigned short Klds[64 * 72];  // 9216 B
    __shared__ __align__(16) unsigned short Vlds[64 * 72];  // 9216 B

    const int bh = (int)blockIdx.x + ((int)blockIdx.y >> 3) * 8;  // bx + 8*(by/8)
    const int qb = blockIdx.y & 7;                                // 0..7
    const int b = bh / 12, h = bh % 12;
    const int wave = threadIdx.x >> 6, lane = threadIdx.x & 63;
    const int lrow = lane & 15, quad = lane >> 4;
    const int qrow0 = qb * 128 + wave * 32;

    const unsigned short* Qb = Q + (size_t)bh * 65536;
    const unsigned short* Kb = K + (size_t)bh * 65536;
    const unsigned short* Vb = Vt + (size_t)bh * 65536;

    // staging coords: 8 chunks of 8 u16 per row, rows trow and trow+32
    const int tch = threadIdx.x & 7, trow = threadIdx.x >> 3;
    // K slot permutation: slot(r) inverts kv = (lrow>>2)*8+(lrow&3)+4*tau
    // so that reads are at linear row w*32 + tau*16 + lrow.
    const int slot0 = ((trow & 4) << 2) | ((trow >> 3) << 2) | (trow & 3);

    short8 aq[2][2];
    #pragma unroll
    for (int mm = 0; mm < 2; ++mm) {
        const unsigned short* qr = Qb + (size_t)(qrow0 + mm * 16 + lrow) * 64;
        aq[mm][0] = *(const short8*)(qr + quad * 8);
        aq[mm][1] = *(const short8*)(qr + 32 + quad * 8);
    }

    const floatx4 zero = { 0.f, 0.f, 0.f, 0.f };
    float part[2] = { 0.f, 0.f };
    floatx4 Oacc[2][4];
    #pragma unroll
    for (int mm = 0; mm < 2; ++mm)
        #pragma unroll
        for (int t = 0; t < 4; ++t) Oacc[mm][t] = zero;

    // ---- prologue: prefetch tile 0 into registers ----
    short8 kpre[2], vpre[2];
    kpre[0] = *(const short8*)(Kb + (size_t)trow * 64 + tch * 8);
    kpre[1] = *(const short8*)(Kb + (size_t)(trow + 32) * 64 + tch * 8);
    vpre[0] = *(const short8*)(Vb + (size_t)trow * 1024 + tch * 8);
    vpre[1] = *(const short8*)(Vb + (size_t)(trow + 32) * 1024 + tch * 8);

    for (int jt = 0; jt < 16; ++jt) {
        // ---- write staged registers to LDS (K rows slot-permuted) ----
        *(short8*)&Klds[slot0 * 72 + tch * 8] = kpre[0];
        *(short8*)&Klds[(slot0 + 32) * 72 + tch * 8] = kpre[1];
        *(short8*)&Vlds[trow * 72 + tch * 8] = vpre[0];
        *(short8*)&Vlds[(trow + 32) * 72 + tch * 8] = vpre[1];
        __syncthreads();

        // ---- issue next tile's global loads (in flight during compute) ----
        {
            const int jn = ((jt + 1) & 15) * 64;  // wraps harmlessly
            kpre[0] = *(const short8*)(Kb + (size_t)(jn + trow) * 64 + tch * 8);
            kpre[1] = *(const short8*)(Kb + (size_t)(jn + trow + 32) * 64 + tch * 8);
            vpre[0] = *(const short8*)(Vb + (size_t)trow * 1024 + jn + tch * 8);
            vpre[1] = *(const short8*)(Vb + (size_t)(trow + 32) * 1024 + jn + tch * 8);
        }

        // ---- compute: 2 windows x 2 m-tiles ----
        #pragma unroll
        for (int w = 0; w < 2; ++w) {
            short8 kA[2][2];
            #pragma unroll
            for (int tau = 0; tau < 2; ++tau) {
                int kr = w * 32 + tau * 16 + lrow;  // linear (slot-permuted)
                kA[tau][0] = *(const short8*)&Klds[kr * 72 + quad * 8];
                kA[tau][1] = *(const short8*)&Klds[kr * 72 + 32 + quad * 8];
            }
            short8 vA[4];
            #pragma unroll
            for (int t = 0; t < 4; ++t)
                vA[t] = *(const short8*)&Vlds[(t * 16 + lrow) * 72
                                              + w * 32 + quad * 8];

            #pragma unroll
            for (int mm = 0; mm < 2; ++mm) {
                floatx4 s0 = zero, s1 = zero;
                s0 = MFMA16(kA[0][0], aq[mm][0], s0);
                s0 = MFMA16(kA[0][1], aq[mm][1], s0);
                s1 = MFMA16(kA[1][0], aq[mm][0], s1);
                s1 = MFMA16(kA[1][1], aq[mm][1], s1);

                short8 pk;
                #pragma unroll
                for (int r = 0; r < 4; ++r) {
                    float p0 = EXP2(s0[r]);
                    float p1 = EXP2(s1[r]);
                    part[mm] += p0 + p1;
                    pk[r] = (short)f2bf_trunc(p0);
                    pk[4 + r] = (short)f2bf_trunc(p1);
                }
                #pragma unroll
                for (int t = 0; t < 4; ++t)
                    Oacc[mm][t] = MFMA16(vA[t], pk, Oacc[mm][t]);
            }
        }
        __syncthreads();
    }

    // ---- epilogue ----
    #pragma unroll
    for (int mm = 0; mm < 2; ++mm) {
        float ts = part[mm];
        ts += __shfl_xor(ts, 16);
        ts += __shfl_xor(ts, 32);
        float inv = RCP(ts);
        unsigned short* orow = AO
            + ((size_t)(b * 1024 + qrow0 + mm * 16 + lrow)) * 768 + h * 64;
        #pragma unroll
        for (int t = 0; t < 4; ++t) {
            unsigned short pkd[4];
            #pragma unroll
            for (int r = 0; r < 4; ++r)
                pkd[r] = f2bf(Oacc[mm][t][r] * inv);
            *(uint2*)(orow + t * 16 + quad * 4) = *(uint2*)pkd;  // 8B store
        }
    }
}

// ---------------------------------------------------------------------------
// Phase 3 (round-13): staged GEMM, transposed compute, float4 Y stores.
// Tile 128x64, BK=32. grid (64, 12), block 256 = 2x2 waves of 64row x 32c.
// ---------------------------------------------------------------------------
__global__ __launch_bounds__(256) void out_proj(
    const unsigned short* __restrict__ AO, const unsigned short* __restrict__ Wob,
    const float* __restrict__ bo, float* __restrict__ Y)
{
    __shared__ __align__(16) unsigned short Alds[128 * 40];  // 10240 B
    __shared__ __align__(16) unsigned short Blds[64 * 40];   //  5120 B

    const int wave = threadIdx.x >> 6, lane = threadIdx.x & 63;
    const int lrow = lane & 15, quad = lane >> 4;
    const int row0 = blockIdx.x * 128;
    const int c0 = blockIdx.y * 64;
    const int wrow = (wave >> 1) * 64, wcol = (wave & 1) * 32;

    const int tch = threadIdx.x & 3, trow = threadIdx.x >> 2;  // 64 rows/round

    const floatx4 zero = { 0.f, 0.f, 0.f, 0.f };
    floatx4 acc[2][4];  // [c-subtile u][row-subtile t]
    #pragma unroll
    for (int u = 0; u < 2; ++u)
        #pragma unroll
        for (int t = 0; t < 4; ++t) acc[u][t] = zero;

    for (int k0 = 0; k0 < 768; k0 += 32) {
        #pragma unroll
        for (int rr = 0; rr < 2; ++rr) {
            int r = trow + rr * 64;
            *(short8*)&Alds[r * 40 + tch * 8] =
                *(const short8*)(AO + (size_t)(row0 + r) * 768 + k0 + tch * 8);
        }
        *(short8*)&Blds[trow * 40 + tch * 8] =
            *(const short8*)(Wob + (size_t)(c0 + trow) * 768 + k0 + tch * 8);
        __syncthreads();

        short8 aoF[4], wF[2];
        #pragma unroll
        for (int t = 0; t < 4; ++t)
            aoF[t] = *(const short8*)&Alds[(wrow + t * 16 + lrow) * 40 + quad * 8];
        #pragma unroll
        for (int u = 0; u < 2; ++u)
            wF[u] = *(const short8*)&Blds[(wcol + u * 16 + lrow) * 40 + quad * 8];

        #pragma unroll
        for (int u = 0; u < 2; ++u)
            #pragma unroll
            for (int t = 0; t < 4; ++t)
                acc[u][t] = MFMA16(wF[u], aoF[t], acc[u][t]);  // D[c][row]
        __syncthreads();
    }

    #pragma unroll
    for (int u = 0; u < 2; ++u) {
        const int cb = c0 + wcol + u * 16 + quad * 4;
        float4 bias = *(const float4*)(bo + cb);
        const float bs[4] = { bias.x, bias.y, bias.z, bias.w };
        #pragma unroll
        for (int t = 0; t < 4; ++t) {
            const int row = row0 + wrow + t * 16 + lrow;
            float out[4];
            #pragma unroll
            for (int r = 0; r < 4; ++r) out[r] = acc[u][t][r] + bs[r];
            *(float4*)(Y + (size_t)row * 768 + cb) = *(float4*)out;  // 16B store
        }
    }
}

extern "C" void kernel_launch(void* const* d_in, const int* in_sizes, int n_in,
                              void* d_out, int out_size, void* d_ws, size_t ws_size,
                              hipStream_t stream)
{
    const float* x  = (const float*)d_in[0];
    const float* Wq = (const float*)d_in[1];
    const float* Wk = (const float*)d_in[2];
    const float* Wv = (const float*)d_in[3];
    const float* bq = (const float*)d_in[4];
    const float* bk = (const float*)d_in[5];
    const float* bv = (const float*)d_in[6];
    const float* Wo = (const float*)d_in[7];
    const float* bo = (const float*)d_in[8];

    // ws layout (bf16 elements)
    unsigned short* Q   = (unsigned short*)d_ws;        // 6291456
    unsigned short* K   = Q + 6291456;                  // 6291456
    unsigned short* Vt  = K + 6291456;                  // 6291456 (transposed)
    unsigned short* AO  = Vt + 6291456;                 // 6291456
    unsigned short* Wqt = AO + 6291456;                 // 49152
    unsigned short* Wkt = Wqt + 49152;                  // 49152
    unsigned short* Wvt = Wkt + 49152;                  // 49152
    unsigned short* Wob = Wvt + 49152;                  // 589824
    float* Y = (float*)d_out;

    prep_weights<<<dim3(576), 256, 0, stream>>>(Wq, Wk, Wv, Wo, Wqt, Wkt, Wvt, Wob);
    qkv_proj<<<dim3(16, 96), 256, 0, stream>>>(x, Wqt, Wkt, Wvt, bq, bk, bv, Q, K, Vt);
    attn_kernel<<<dim3(8, 96), 256, 0, stream>>>(Q, K, Vt, AO);
    out_proj<<<dim3(64, 12), 256, 0, stream>>>(AO, Wob, bo, Y);
}

// Round 15
// 169.571 us; speedup vs baseline: 1.0422x; 1.0224x over previous
//
#include <hip/hip_runtime.h>

// MHA: B=8, N=1024, D=768, H=12, HD=64. FLOAT32 in/out, bf16 MFMA internally.
// Round 15: qkv x-staging fully coalesced (16 lanes/row); out_proj BK=64 with
// register-prefetched staging (half the barriers, loads in flight).
// attn (42.4us, round 14) and prep unchanged.

typedef __attribute__((ext_vector_type(8))) short short8;   // 8 x bf16 bits
typedef __attribute__((ext_vector_type(4))) float floatx4;  // MFMA acc

#define MFMA16(a, b, c) __builtin_amdgcn_mfma_f32_16x16x32_bf16((a), (b), (c), 0, 0, 0)

#if __has_builtin(__builtin_amdgcn_exp2f)
#define EXP2(x) __builtin_amdgcn_exp2f(x)
#else
#define EXP2(x) __expf(0.6931471805599453f * (x))
#endif
#if __has_builtin(__builtin_amdgcn_rcpf)
#define RCP(x) __builtin_amdgcn_rcpf(x)
#else
#define RCP(x) (1.0f / (x))
#endif

__device__ __forceinline__ unsigned short f2bf(float f) {
    union { float f; unsigned int i; } c;
    c.f = f;
    unsigned int i = c.i;
    return (unsigned short)((i + 0x7fffu + ((i >> 16) & 1u)) >> 16);  // RNE
}
__device__ __forceinline__ unsigned short f2bf_trunc(float f) {
    union { float f; unsigned int i; } c;
    c.f = f;
    return (unsigned short)(c.i >> 16);
}

// ---------------------------------------------------------------------------
// Phase 0: Wt[h][e][k] = W[h][k][e] (bf16), Wo_bf = bf16(Wo).
// ---------------------------------------------------------------------------
__global__ __launch_bounds__(256) void prep_weights(
    const float* __restrict__ Wq, const float* __restrict__ Wk,
    const float* __restrict__ Wv, const float* __restrict__ Wo,
    unsigned short* __restrict__ Wqt, unsigned short* __restrict__ Wkt,
    unsigned short* __restrict__ Wvt, unsigned short* __restrict__ Wob)
{
    int tid = blockIdx.x * 256 + threadIdx.x;  // 0..147455
    if (tid < 49152) {                          // 12 heads * 4096 only
        int h = tid >> 12, r = tid & 4095;
        int e = r >> 6, k = r & 63;
        int src = h * 4096 + k * 64 + e, dst = h * 4096 + e * 64 + k;
        Wqt[dst] = f2bf(Wq[src]);
        Wkt[dst] = f2bf(Wk[src]);
        Wvt[dst] = f2bf(Wv[src]);
    }
    for (int i = tid; i < 589824; i += 147456) Wob[i] = f2bf(Wo[i]);
}

// ---------------------------------------------------------------------------
// Phase 1: staged + transposed QKV. grid (16, 96), block 256.
// x staging now fully coalesced: 16 lanes cover one row (256 B segments).
// ---------------------------------------------------------------------------
__global__ __launch_bounds__(256) void qkv_proj(
    const float* __restrict__ x,
    const unsigned short* __restrict__ Wqt, const unsigned short* __restrict__ Wkt,
    const unsigned short* __restrict__ Wvt,
    const float* __restrict__ bq, const float* __restrict__ bk,
    const float* __restrict__ bv,
    unsigned short* __restrict__ Q, unsigned short* __restrict__ K,
    unsigned short* __restrict__ Vt)
{
    __shared__ __align__(16) unsigned short xlds[64 * 72];  // 9216 B
    __shared__ __align__(16) unsigned short vlds[64 * 72];  // 9216 B

    const int bh = blockIdx.y;
    const int b = bh / 12, h = bh % 12;
    const int wave = threadIdx.x >> 6, lane = threadIdx.x & 63;
    const int lrow = lane & 15, quad = lane >> 4;
    const int row0 = blockIdx.x * 64;
    const float scale = 0.052058776672f;  // 768^-0.5 * log2(e): p = 2^s

    // ---- stage x tile, coalesced: 16 lanes per row, one float4 each ----
    {
        const int tr = threadIdx.x >> 4;        // 16 rows per round
        const int tc = (threadIdx.x & 15) * 4;  // 4 f32 per thread
        #pragma unroll
        for (int rr = 0; rr < 4; ++rr) {
            const int r = tr + rr * 16;
            const float* src = x + ((size_t)(b * 1024 + row0 + r)) * 768
                               + h * 64 + tc;
            float4 f = *(const float4*)src;
            unsigned short pkd[4];
            pkd[0] = f2bf(f.x); pkd[1] = f2bf(f.y);
            pkd[2] = f2bf(f.z); pkd[3] = f2bf(f.w);
            *(uint2*)&xlds[r * 72 + tc] = *(uint2*)pkd;  // 8B LDS write
        }
    }
    __syncthreads();

    short8 xb0 = *(const short8*)&xlds[(wave * 16 + lrow) * 72 + quad * 8];
    short8 xb1 = *(const short8*)&xlds[(wave * 16 + lrow) * 72 + 32 + quad * 8];

    const floatx4 zero = { 0.f, 0.f, 0.f, 0.f };

    const unsigned short* Wm[2] = { Wqt + h * 4096, Wkt + h * 4096 };
    const float* bm[2] = { bq + h * 64, bk + h * 64 };
    unsigned short* Om[2] = {
        Q + ((size_t)bh * 1024 + row0 + wave * 16 + lrow) * 64,
        K + ((size_t)bh * 1024 + row0 + wave * 16 + lrow) * 64 };
    #pragma unroll
    for (int m = 0; m < 2; ++m) {
        const unsigned short* W = Wm[m];
        #pragma unroll
        for (int t = 0; t < 4; ++t) {
            short8 wa0 = *(const short8*)(W + (t * 16 + lrow) * 64 + quad * 8);
            short8 wa1 = *(const short8*)(W + (t * 16 + lrow) * 64 + 32 + quad * 8);
            floatx4 acc = zero;
            acc = MFMA16(wa0, xb0, acc);
            acc = MFMA16(wa1, xb1, acc);
            float4 bias = *(const float4*)(bm[m] + t * 16 + quad * 4);
            const float bs[4] = { bias.x, bias.y, bias.z, bias.w };
            unsigned short pkd[4];
            #pragma unroll
            for (int r = 0; r < 4; ++r) {
                float v = acc[r] + bs[r];
                if (m == 0) v *= scale;
                pkd[r] = f2bf(v);
            }
            *(uint2*)(Om[m] + t * 16 + quad * 4) = *(uint2*)pkd;  // 8B store
        }
    }

    {
        const unsigned short* W = Wvt + h * 4096;
        const float* bvh = bv + h * 64;
        #pragma unroll
        for (int t = 0; t < 4; ++t) {
            short8 wa0 = *(const short8*)(W + (t * 16 + lrow) * 64 + quad * 8);
            short8 wa1 = *(const short8*)(W + (t * 16 + lrow) * 64 + 32 + quad * 8);
            floatx4 acc = zero;
            acc = MFMA16(wa0, xb0, acc);
            acc = MFMA16(wa1, xb1, acc);
            float4 bias = *(const float4*)(bvh + t * 16 + quad * 4);
            const float bs[4] = { bias.x, bias.y, bias.z, bias.w };
            #pragma unroll
            for (int r = 0; r < 4; ++r)
                vlds[(t * 16 + quad * 4 + r) * 72 + wave * 16 + lrow]
                    = f2bf(acc[r] + bs[r]);
        }
    }
    __syncthreads();
    {
        const int er = threadIdx.x >> 2;   // e row 0..63
        const int sc = threadIdx.x & 3;    // chunk of 16 seq
        short8 v0 = *(const short8*)&vlds[er * 72 + sc * 16];
        short8 v1 = *(const short8*)&vlds[er * 72 + sc * 16 + 8];
        unsigned short* dst = Vt + (size_t)bh * 65536 + (size_t)er * 1024
                              + row0 + sc * 16;
        *(short8*)dst = v0;
        *(short8*)(dst + 8) = v1;
    }
}

// ---------------------------------------------------------------------------
// Phase 2 (round-14, unchanged): flash attention, M=32/wave, prefetched
// staging, slot-permuted K LDS, register-only P. grid (8, 96), block 256.
// ---------------------------------------------------------------------------
__global__ __launch_bounds__(256) void attn_kernel(
    const unsigned short* __restrict__ Q, const unsigned short* __restrict__ K,
    const unsigned short* __restrict__ Vt, unsigned short* __restrict__ AO)
{
    __shared__ __align__(16) unsigned short Klds[64 * 72];  // 9216 B
    __shared__ __align__(16) unsigned short Vlds[64 * 72];  // 9216 B

    const int bh = (int)blockIdx.x + ((int)blockIdx.y >> 3) * 8;
    const int qb = blockIdx.y & 7;
    const int b = bh / 12, h = bh % 12;
    const int wave = threadIdx.x >> 6, lane = threadIdx.x & 63;
    const int lrow = lane & 15, quad = lane >> 4;
    const int qrow0 = qb * 128 + wave * 32;

    const unsigned short* Qb = Q + (size_t)bh * 65536;
    const unsigned short* Kb = K + (size_t)bh * 65536;
    const unsigned short* Vb = Vt + (size_t)bh * 65536;

    const int tch = threadIdx.x & 7, trow = threadIdx.x >> 3;
    const int slot0 = ((trow & 4) << 2) | ((trow >> 3) << 2) | (trow & 3);

    short8 aq[2][2];
    #pragma unroll
    for (int mm = 0; mm < 2; ++mm) {
        const unsigned short* qr = Qb + (size_t)(qrow0 + mm * 16 + lrow) * 64;
        aq[mm][0] = *(const short8*)(qr + quad * 8);
        aq[mm][1] = *(const short8*)(qr + 32 + quad * 8);
    }

    const floatx4 zero = { 0.f, 0.f, 0.f, 0.f };
    float part[2] = { 0.f, 0.f };
    floatx4 Oacc[2][4];
    #pragma unroll
    for (int mm = 0; mm < 2; ++mm)
        #pragma unroll
        for (int t = 0; t < 4; ++t) Oacc[mm][t] = zero;

    short8 kpre[2], vpre[2];
    kpre[0] = *(const short8*)(Kb + (size_t)trow * 64 + tch * 8);
    kpre[1] = *(const short8*)(Kb + (size_t)(trow + 32) * 64 + tch * 8);
    vpre[0] = *(const short8*)(Vb + (size_t)trow * 1024 + tch * 8);
    vpre[1] = *(const short8*)(Vb + (size_t)(trow + 32) * 1024 + tch * 8);

    for (int jt = 0; jt < 16; ++jt) {
        *(short8*)&Klds[slot0 * 72 + tch * 8] = kpre[0];
        *(short8*)&Klds[(slot0 + 32) * 72 + tch * 8] = kpre[1];
        *(short8*)&Vlds[trow * 72 + tch * 8] = vpre[0];
        *(short8*)&Vlds[(trow + 32) * 72 + tch * 8] = vpre[1];
        __syncthreads();

        {
            const int jn = ((jt + 1) & 15) * 64;
            kpre[0] = *(const short8*)(Kb + (size_t)(jn + trow) * 64 + tch * 8);
            kpre[1] = *(const short8*)(Kb + (size_t)(jn + trow + 32) * 64 + tch * 8);
            vpre[0] = *(const short8*)(Vb + (size_t)trow * 1024 + jn + tch * 8);
            vpre[1] = *(const short8*)(Vb + (size_t)(trow + 32) * 1024 + jn + tch * 8);
        }

        #pragma unroll
        for (int w = 0; w < 2; ++w) {
            short8 kA[2][2];
            #pragma unroll
            for (int tau = 0; tau < 2; ++tau) {
                int kr = w * 32 + tau * 16 + lrow;
                kA[tau][0] = *(const short8*)&Klds[kr * 72 + quad * 8];
                kA[tau][1] = *(const short8*)&Klds[kr * 72 + 32 + quad * 8];
            }
            short8 vA[4];
            #pragma unroll
            for (int t = 0; t < 4; ++t)
                vA[t] = *(const short8*)&Vlds[(t * 16 + lrow) * 72
                                              + w * 32 + quad * 8];

            #pragma unroll
            for (int mm = 0; mm < 2; ++mm) {
                floatx4 s0 = zero, s1 = zero;
                s0 = MFMA16(kA[0][0], aq[mm][0], s0);
                s0 = MFMA16(kA[0][1], aq[mm][1], s0);
                s1 = MFMA16(kA[1][0], aq[mm][0], s1);
                s1 = MFMA16(kA[1][1], aq[mm][1], s1);

                short8 pk;
                #pragma unroll
                for (int r = 0; r < 4; ++r) {
                    float p0 = EXP2(s0[r]);
                    float p1 = EXP2(s1[r]);
                    part[mm] += p0 + p1;
                    pk[r] = (short)f2bf_trunc(p0);
                    pk[4 + r] = (short)f2bf_trunc(p1);
                }
                #pragma unroll
                for (int t = 0; t < 4; ++t)
                    Oacc[mm][t] = MFMA16(vA[t], pk, Oacc[mm][t]);
            }
        }
        __syncthreads();
    }

    #pragma unroll
    for (int mm = 0; mm < 2; ++mm) {
        float ts = part[mm];
        ts += __shfl_xor(ts, 16);
        ts += __shfl_xor(ts, 32);
        float inv = RCP(ts);
        unsigned short* orow = AO
            + ((size_t)(b * 1024 + qrow0 + mm * 16 + lrow)) * 768 + h * 64;
        #pragma unroll
        for (int t = 0; t < 4; ++t) {
            unsigned short pkd[4];
            #pragma unroll
            for (int r = 0; r < 4; ++r)
                pkd[r] = f2bf(Oacc[mm][t][r] * inv);
            *(uint2*)(orow + t * 16 + quad * 4) = *(uint2*)pkd;
        }
    }
}

// ---------------------------------------------------------------------------
// Phase 3: staged GEMM, BK=64 + register-prefetched staging.
// Tile 128x64, 12 k-iters. grid (64, 12), block 256 = 2x2 waves of 64r x 32c.
// Transposed compute D[c][row] -> float4 Y stores.
// ---------------------------------------------------------------------------
__global__ __launch_bounds__(256) void out_proj(
    const unsigned short* __restrict__ AO, const unsigned short* __restrict__ Wob,
    const float* __restrict__ bo, float* __restrict__ Y)
{
    __shared__ __align__(16) unsigned short Alds[128 * 72];  // 18432 B
    __shared__ __align__(16) unsigned short Blds[64 * 72];   //  9216 B

    const int wave = threadIdx.x >> 6, lane = threadIdx.x & 63;
    const int lrow = lane & 15, quad = lane >> 4;
    const int row0 = blockIdx.x * 128;
    const int c0 = blockIdx.y * 64;
    const int wrow = (wave >> 1) * 64, wcol = (wave & 1) * 32;

    // staging coords: 8 chunks of 8 u16 per 64-col row; 32 rows per round
    const int tch = threadIdx.x & 7, trow = threadIdx.x >> 3;

    const floatx4 zero = { 0.f, 0.f, 0.f, 0.f };
    floatx4 acc[2][4];  // [c-subtile u][row-subtile t]
    #pragma unroll
    for (int u = 0; u < 2; ++u)
        #pragma unroll
        for (int t = 0; t < 4; ++t) acc[u][t] = zero;

    // prologue: prefetch k-tile 0 (A: rows trow, +32, +64, +96; B: trow, +32)
    short8 apre[4], bpre[2];
    #pragma unroll
    for (int rr = 0; rr < 4; ++rr)
        apre[rr] = *(const short8*)(AO + (size_t)(row0 + trow + rr * 32) * 768
                                    + tch * 8);
    #pragma unroll
    for (int rr = 0; rr < 2; ++rr)
        bpre[rr] = *(const short8*)(Wob + (size_t)(c0 + trow + rr * 32) * 768
                                    + tch * 8);

    for (int k0 = 0; k0 < 768; k0 += 64) {
        // write staged registers
        #pragma unroll
        for (int rr = 0; rr < 4; ++rr)
            *(short8*)&Alds[(trow + rr * 32) * 72 + tch * 8] = apre[rr];
        #pragma unroll
        for (int rr = 0; rr < 2; ++rr)
            *(short8*)&Blds[(trow + rr * 32) * 72 + tch * 8] = bpre[rr];
        __syncthreads();

        // issue next k-tile's loads (wraps harmlessly on the last iter)
        {
            const int kn = (k0 + 64 < 768) ? k0 + 64 : 0;
            #pragma unroll
            for (int rr = 0; rr < 4; ++rr)
                apre[rr] = *(const short8*)(AO
                    + (size_t)(row0 + trow + rr * 32) * 768 + kn + tch * 8);
            #pragma unroll
            for (int rr = 0; rr < 2; ++rr)
                bpre[rr] = *(const short8*)(Wob
                    + (size_t)(c0 + trow + rr * 32) * 768 + kn + tch * 8);
        }

        // compute: 2 k-chunks of 32, 8 MFMA each
        #pragma unroll
        for (int kc = 0; kc < 2; ++kc) {
            short8 aoF[4], wF[2];
            #pragma unroll
            for (int t = 0; t < 4; ++t)
                aoF[t] = *(const short8*)&Alds[(wrow + t * 16 + lrow) * 72
                                               + kc * 32 + quad * 8];
            #pragma unroll
            for (int u = 0; u < 2; ++u)
                wF[u] = *(const short8*)&Blds[(wcol + u * 16 + lrow) * 72
                                              + kc * 32 + quad * 8];
            #pragma unroll
            for (int u = 0; u < 2; ++u)
                #pragma unroll
                for (int t = 0; t < 4; ++t)
                    acc[u][t] = MFMA16(wF[u], aoF[t], acc[u][t]);  // D[c][row]
        }
        __syncthreads();
    }

    #pragma unroll
    for (int u = 0; u < 2; ++u) {
        const int cb = c0 + wcol + u * 16 + quad * 4;
        float4 bias = *(const float4*)(bo + cb);
        const float bs[4] = { bias.x, bias.y, bias.z, bias.w };
        #pragma unroll
        for (int t = 0; t < 4; ++t) {
            const int row = row0 + wrow + t * 16 + lrow;
            float out[4];
            #pragma unroll
            for (int r = 0; r < 4; ++r) out[r] = acc[u][t][r] + bs[r];
            *(float4*)(Y + (size_t)row * 768 + cb) = *(float4*)out;  // 16B store
        }
    }
}

extern "C" void kernel_launch(void* const* d_in, const int* in_sizes, int n_in,
                              void* d_out, int out_size, void* d_ws, size_t ws_size,
                              hipStream_t stream)
{
    const float* x  = (const float*)d_in[0];
    const float* Wq = (const float*)d_in[1];
    const float* Wk = (const float*)d_in[2];
    const float* Wv = (const float*)d_in[3];
    const float* bq = (const float*)d_in[4];
    const float* bk = (const float*)d_in[5];
    const float* bv = (const float*)d_in[6];
    const float* Wo = (const float*)d_in[7];
    const float* bo = (const float*)d_in[8];

    // ws layout (bf16 elements)
    unsigned short* Q   = (unsigned short*)d_ws;        // 6291456
    unsigned short* K   = Q + 6291456;                  // 6291456
    unsigned short* Vt  = K + 6291456;                  // 6291456 (transposed)
    unsigned short* AO  = Vt + 6291456;                 // 6291456
    unsigned short* Wqt = AO + 6291456;                 // 49152
    unsigned short* Wkt = Wqt + 49152;                  // 49152
    unsigned short* Wvt = Wkt + 49152;                  // 49152
    unsigned short* Wob = Wvt + 49152;                  // 589824
    float* Y = (float*)d_out;

    prep_weights<<<dim3(576), 256, 0, stream>>>(Wq, Wk, Wv, Wo, Wqt, Wkt, Wvt, Wob);
    qkv_proj<<<dim3(16, 96), 256, 0, stream>>>(x, Wqt, Wkt, Wvt, bq, bk, bv, Q, K, Vt);
    attn_kernel<<<dim3(8, 96), 256, 0, stream>>>(Q, K, Vt, AO);
    out_proj<<<dim3(64, 12), 256, 0, stream>>>(AO, Wob, bo, Y);
}